// Round 6
// baseline (1299.139 us; speedup 1.0000x reference)
//
#include <hip/hip_runtime.h>

// ---------------------------------------------------------------------------
// GAT (2-layer, dense mask) on gfx950 — R6: ONE persistent kernel.
// R1..R5 showed total-minus-att1 stuck at ~140-150 us while per-kernel GPU
// estimates sum to ~40 us => ~10 us/launch serialization overhead. Fuse all
// 8 stages into one 1024-block kernel with manual device-scope grid barriers
// (sense-reversing, all blocks co-resident by __launch_bounds__(256,4) +
// LDS <= 20 KB). att1 keeps the R3 structure (best measured), bf16 partial
// buffers, no atomics (R5's atomic write-through was the regression).
// ---------------------------------------------------------------------------

typedef __attribute__((ext_vector_type(8))) short short8;   // 8 x bf16
typedef __attribute__((ext_vector_type(4))) float f32x4;
typedef unsigned long long u64;
typedef unsigned short u16;
typedef unsigned int u32;

#define NBLK 1024

__device__ __forceinline__ u16 f2bf_rne(float f){
  u32 u = __float_as_uint(f);
  return (u16)((u + 0x7fffu + ((u >> 16) & 1u)) >> 16);
}
__device__ __forceinline__ void async16(void* lds, const void* g){
  __builtin_amdgcn_global_load_lds((const __attribute__((address_space(1))) u32*)g,
                                   (__attribute__((address_space(3))) u32*)lds, 16, 0, 0);
}
__device__ __forceinline__ void async4(void* lds, const void* g){
  __builtin_amdgcn_global_load_lds((const __attribute__((address_space(1))) u32*)g,
                                   (__attribute__((address_space(3))) u32*)lds, 4, 0, 0);
}

// sense-reversing grid barrier; bar[0]=arrive counter, bar[1]=generation
__device__ __forceinline__ void grid_barrier(u32* bar){
  __syncthreads();
  if (threadIdx.x == 0){
    __threadfence();   // release prior global writes device-wide
    u32 gen = __hip_atomic_load(&bar[1], __ATOMIC_RELAXED, __HIP_MEMORY_SCOPE_AGENT);
    u32 arr = __hip_atomic_fetch_add(&bar[0], 1u, __ATOMIC_ACQ_REL, __HIP_MEMORY_SCOPE_AGENT);
    if (arr == (u32)NBLK - 1u){
      __hip_atomic_store(&bar[0], 0u, __ATOMIC_RELAXED, __HIP_MEMORY_SCOPE_AGENT);
      __hip_atomic_fetch_add(&bar[1], 1u, __ATOMIC_RELEASE, __HIP_MEMORY_SCOPE_AGENT);
    } else {
      while (__hip_atomic_load(&bar[1], __ATOMIC_ACQUIRE, __HIP_MEMORY_SCOPE_AGENT) == gen)
        __builtin_amdgcn_s_sleep(2);
    }
    __threadfence();
  }
  __syncthreads();
}

__global__ __launch_bounds__(256, 4) void k_gat(
    const float* __restrict__ x, const int* __restrict__ adj,
    const float* __restrict__ W, const float* __restrict__ av,
    const float* __restrict__ Wout, const float* __restrict__ aout,
    float* __restrict__ out,
    u32* bar, u64* adjbits, u16* xA, u16* wB, u16* whB,
    float* e11, float* e102, float* e21, float* e202,
    u16* pnum1, float* pden1, u16* whoB,
    float* e11o, float* e102o, float* e21o, float* e202o,
    float* pnum2, float* pden2)
{
  __shared__ __align__(16) char smem[20480];
  u16*   s_tr   = (u16*)smem;                 // P1: 8 KB transpose
  u16*   s_B    = (u16*)smem;                 // P2: 2 x 8 KB B tiles
  float* s_T    = (float*)(smem + 16384);     // P2: 2 x 2 x 64 f32 tables (1 KB)
  float* s_hrow = (float*)smem;               // P3: 4 x 512 f32 (8 KB)
  float* s_red  = (float*)(smem + 8192);      // P3: 256 f32 (1 KB)
  u32*   s_lut  = (u32*)(smem + 18432);       // mask LUT (16 B), persists

  const int tid  = threadIdx.x;
  const int lane = tid & 63;
  const int wv   = tid >> 6;
  const int row16 = lane & 15, grp = lane >> 4;
  const int b = blockIdx.x;

  if (tid < 4)
    s_lut[tid] = ((tid & 1) ? 0xFFFFu : 0u) | ((tid & 2) ? 0xFFFF0000u : 0u);

  // ======================= P0: adj bitmask + input packs ===================
  {  // pack x -> A-layout bf16 (all 1024 blocks, 1 unit/thread)
    int t = b * 256 + tid;                    // 262144
    int n = t & 4095, fg = t >> 12;
    const float* src = x + (size_t)n * 512 + fg * 8;
    float4 v0 = ((const float4*)src)[0];
    float4 v1 = ((const float4*)src)[1];
    u32 pk[4];
    pk[0] = f2bf_rne(v0.x) | ((u32)f2bf_rne(v0.y) << 16);
    pk[1] = f2bf_rne(v0.z) | ((u32)f2bf_rne(v0.w) << 16);
    pk[2] = f2bf_rne(v1.x) | ((u32)f2bf_rne(v1.y) << 16);
    pk[3] = f2bf_rne(v1.z) | ((u32)f2bf_rne(v1.w) << 16);
    *(uint4*)(xA + ((size_t)fg * 4096 + n) * 8) = *(uint4*)pk;
  }
  if (b < 128){  // pack W -> B-layout bf16
    int t = b * 256 + tid;                    // 32768
    int o = t & 63, fg = (t >> 6) & 63, h = t >> 12;
    const float* src = W + ((size_t)h * 512 + fg * 8) * 64 + o;
    u32 pk[4];
    #pragma unroll
    for (int p = 0; p < 4; ++p){
      u16 lo = f2bf_rne(src[(2 * p) * 64]);
      u16 hi = f2bf_rne(src[(2 * p + 1) * 64]);
      pk[p] = lo | ((u32)hi << 16);
    }
    *(uint4*)(wB + (size_t)h * 32768 + ((size_t)fg * 64 + o) * 8) = *(uint4*)pk;
  }
  {  // adj -> bitmask (4096 waves x 64 units)
    int w0 = b * 4 + wv;
    #pragma unroll 4
    for (int k = 0; k < 64; ++k){
      int wid = w0 + k * 4096;
      int i = wid >> 6, jg = wid & 63;
      int v = adj[(size_t)i * 4096 + (jg << 6) + lane];
      u64 m = __ballot(v != 0);
      if (lane == 0) adjbits[(size_t)i * 64 + jg] = m;
    }
  }
  grid_barrier(bar);

  // ======================= P1: Wh = x@W[h] + tables + whB pack =============
  if (b < 512){
    int h = b >> 6, nblk = b & 63;
    int n0 = nblk * 64, n0w = n0 + wv * 16;
    const u16* wBh = wB + (size_t)h * 32768;
    f32x4 acc[4] = {};
    #pragma unroll 4
    for (int ks = 0; ks < 16; ++ks){
      int fgb = ks * 4 + grp;
      short8 af = *(const short8*)(xA + ((size_t)fgb * 4096 + n0w + row16) * 8);
      #pragma unroll
      for (int nt = 0; nt < 4; ++nt){
        short8 bf = *(const short8*)(wBh + ((size_t)fgb * 64 + nt * 16 + row16) * 8);
        acc[nt] = __builtin_amdgcn_mfma_f32_16x16x32_bf16(af, bf, acc[nt], 0, 0, 0);
      }
    }
    float a1v[4], a2v[4];
    #pragma unroll
    for (int nt = 0; nt < 4; ++nt){
      a1v[nt] = av[h * 128 + nt * 16 + row16];
      a2v[nt] = av[h * 128 + 64 + nt * 16 + row16];
    }
    #pragma unroll
    for (int r = 0; r < 4; ++r){
      float p1 = acc[0][r]*a1v[0] + acc[1][r]*a1v[1] + acc[2][r]*a1v[2] + acc[3][r]*a1v[3];
      float p2 = acc[0][r]*a2v[0] + acc[1][r]*a2v[1] + acc[2][r]*a2v[2] + acc[3][r]*a2v[3];
      #pragma unroll
      for (int d = 1; d < 16; d <<= 1){ p1 += __shfl_xor(p1, d, 64); p2 += __shfl_xor(p2, d, 64); }
      if (row16 == 0){
        int idx = h * 4096 + n0w + grp * 4 + r;
        e11[idx] = __expf(p1); e102[idx] = __expf(0.2f * p1);
        e21[idx] = __expf(p2); e202[idx] = __expf(0.2f * p2);
      }
    }
    #pragma unroll
    for (int nt = 0; nt < 4; ++nt)
      #pragma unroll
      for (int r = 0; r < 4; ++r){
        int jl = wv * 16 + grp * 4 + r;
        int o  = nt * 16 + row16;
        s_tr[((jl >> 3) * 64 + o) * 8 + (jl & 7)] = f2bf_rne(acc[nt][r]);
      }
    __syncthreads();
    u16* dst = whB + (size_t)h * 262144 + (size_t)n0 * 64;
    #pragma unroll
    for (int q = 0; q < 2; ++q)
      *(uint4*)(dst + (tid * 2 + q) * 8) = *(const uint4*)(s_tr + (tid * 2 + q) * 8);
  }
  grid_barrier(bar);

  // ======================= P2: layer-1 attention (R3 body) =================
  {
    int split = b >> 8, h = (b >> 5) & 7, iblk = b & 31;
    int ibase = iblk * 128 + wv * 32;
    int i0 = ibase + row16, i1 = ibase + 16 + row16;
    int hoff = h * 4096;
    float f1a  = e11[hoff + i0],  f1b  = e11[hoff + i1];
    float f02a = e102[hoff + i0], f02b = e102[hoff + i1];
    const u16* whBh = whB + (size_t)h * 262144;
    int jbeg = split * 1024;

    short8 bden;
    #pragma unroll
    for (int t = 0; t < 8; ++t) bden[t] = (row16 == 0) ? (short)0x3F80 : (short)0;

    auto stage = [&](int bb, int j0){
      const char* g = (const char*)whBh + (size_t)j0 * 128 + wv * 2048 + lane * 16;
      char* l = (char*)s_B + bb * 8192 + wv * 2048;
      async16(l, g);
      async16(l + 1024, g + 1024);
      if (wv == 0)      async4(s_T + bb * 128 + lane,      (const char*)(e21  + hoff + j0) + lane * 4);
      else if (wv == 1) async4(s_T + bb * 128 + 64 + lane, (const char*)(e202 + hoff + j0) + lane * 4);
    };

    f32x4 acc[2][4] = {};
    f32x4 accden[2] = {};
    stage(0, jbeg);
    for (int c = 0; c < 16; ++c){
      int bb = c & 1;
      u64 mrow0 = adjbits[(size_t)i0 * 64 + ((jbeg + c * 64) >> 6)];
      u64 mrow1 = adjbits[(size_t)i1 * 64 + ((jbeg + c * 64) >> 6)];
      __syncthreads();
      if (c < 15) stage(bb ^ 1, jbeg + (c + 1) * 64);
      #pragma unroll
      for (int ks = 0; ks < 2; ++ks){
        int kb = ks * 32 + grp * 8;
        const float* tb = s_T + bb * 128;
        float4 eA = *(const float4*)(tb + kb);
        float4 eB = *(const float4*)(tb + kb + 4);
        float4 gA = *(const float4*)(tb + 64 + kb);
        float4 gB = *(const float4*)(tb + 64 + kb + 4);
        float e1v[8] = {eA.x, eA.y, eA.z, eA.w, eB.x, eB.y, eB.z, eB.w};
        float e2v[8] = {gA.x, gA.y, gA.z, gA.w, gB.x, gB.y, gB.z, gB.w};
        const u16* bbase = s_B + bb * 4096 + (ks * 4 + grp) * 512;
        short8 bf0 = *(const short8*)(bbase + (0 * 16 + row16) * 8);
        short8 bf1 = *(const short8*)(bbase + (1 * 16 + row16) * 8);
        short8 bf2 = *(const short8*)(bbase + (2 * 16 + row16) * 8);
        short8 bf3 = *(const short8*)(bbase + (3 * 16 + row16) * 8);
        #pragma unroll
        for (int it = 0; it < 2; ++it){
          u64 mrow = it ? mrow1 : mrow0;
          float f1 = it ? f1b : f1a;
          float f02 = it ? f02b : f02a;
          u32 mb = ((u32)(mrow >> (ks * 32)) >> (grp * 8)) & 0xffu;
          u32 pk[4];
          #pragma unroll
          for (int t2i = 0; t2i < 4; ++t2i){
            float w0 = fmaxf(f1 * e1v[2 * t2i],     f02 * e2v[2 * t2i]);
            float w1 = fmaxf(f1 * e1v[2 * t2i + 1], f02 * e2v[2 * t2i + 1]);
            u32 p = __builtin_amdgcn_perm(__float_as_uint(w1), __float_as_uint(w0), 0x07060302u);
            pk[t2i] = p & s_lut[(mb >> (2 * t2i)) & 3u];
          }
          short8 af = *(short8*)pk;
          acc[it][0] = __builtin_amdgcn_mfma_f32_16x16x32_bf16(af, bf0, acc[it][0], 0, 0, 0);
          acc[it][1] = __builtin_amdgcn_mfma_f32_16x16x32_bf16(af, bf1, acc[it][1], 0, 0, 0);
          acc[it][2] = __builtin_amdgcn_mfma_f32_16x16x32_bf16(af, bf2, acc[it][2], 0, 0, 0);
          acc[it][3] = __builtin_amdgcn_mfma_f32_16x16x32_bf16(af, bf3, acc[it][3], 0, 0, 0);
          accden[it] = __builtin_amdgcn_mfma_f32_16x16x32_bf16(af, bden, accden[it], 0, 0, 0);
        }
      }
    }
    #pragma unroll
    for (int it = 0; it < 2; ++it)
      #pragma unroll
      for (int r = 0; r < 4; ++r){
        int n = ibase + it * 16 + grp * 4 + r;
        if (row16 == 0)
          pden1[((size_t)split * 8 + h) * 4096 + n] = accden[it][r];
        u16* dst = pnum1 + ((size_t)split * 4096 + n) * 512 + h * 64 + row16;
        #pragma unroll
        for (int nt = 0; nt < 4; ++nt)
          dst[nt * 16] = f2bf_rne(acc[it][nt][r]);
      }
  }
  grid_barrier(bar);

  // ======================= P3: combine+elu + Who=h@Wout + tables ===========
  {
    int n0 = b * 4;
    {   // (a) combine 4 splits -> h rows in LDS
      int row = tid >> 6;                      // 0..3
      int fo  = (tid & 63) * 8;
      int hh  = fo >> 6;
      int n   = n0 + row;
      float den = pden1[(0 * 8 + hh) * 4096 + n] + pden1[(1 * 8 + hh) * 4096 + n]
                + pden1[(2 * 8 + hh) * 4096 + n] + pden1[(3 * 8 + hh) * 4096 + n];
      float dinv = 1.f / den;
      float v[8] = {0.f,0.f,0.f,0.f,0.f,0.f,0.f,0.f};
      #pragma unroll
      for (int s = 0; s < 4; ++s){
        uint4 raw = *(const uint4*)(pnum1 + ((size_t)s * 4096 + n) * 512 + fo);
        u32 rw[4] = {raw.x, raw.y, raw.z, raw.w};
        #pragma unroll
        for (int d2 = 0; d2 < 4; ++d2){
          v[d2 * 2]     += __uint_as_float(rw[d2] << 16);
          v[d2 * 2 + 1] += __uint_as_float(rw[d2] & 0xffff0000u);
        }
      }
      #pragma unroll
      for (int j = 0; j < 8; ++j){
        float val = v[j] * dinv;
        val = val > 0.f ? val : (__expf(val) - 1.f);
        s_hrow[row * 512 + fo + j] = val;
      }
    }
    __syncthreads();
    {   // (b) 4-way K-split GEMM vs Wout (L1-resident)
      int c = tid & 15, rl = (tid >> 4) & 3, ks = tid >> 6;
      float acc = 0.f;
      #pragma unroll 8
      for (int f4 = 0; f4 < 32; ++f4){
        int f = ks * 128 + f4 * 4;
        float4 hv = *(const float4*)(s_hrow + rl * 512 + f);
        acc += hv.x * Wout[f * 16 + c] + hv.y * Wout[(f + 1) * 16 + c]
             + hv.z * Wout[(f + 2) * 16 + c] + hv.w * Wout[(f + 3) * 16 + c];
      }
      s_red[tid] = acc;
      __syncthreads();
      if (ks == 0){                            // wave 0 only
        acc += s_red[tid + 64] + s_red[tid + 128] + s_red[tid + 192];
        int n = n0 + rl;
        whoB[((size_t)(n >> 3) * 16 + c) * 8 + (n & 7)] = f2bf_rne(acc);
        float p1 = acc * aout[c], p2 = acc * aout[16 + c];
        #pragma unroll
        for (int d = 1; d < 16; d <<= 1){ p1 += __shfl_xor(p1, d, 64); p2 += __shfl_xor(p2, d, 64); }
        if (c == 0){
          e11o[n] = __expf(p1); e102o[n] = __expf(0.2f * p1);
          e21o[n] = __expf(p2); e202o[n] = __expf(0.2f * p2);
        }
      }
    }
  }
  grid_barrier(bar);

  // ======================= P4: layer-2 attention (global-direct) ===========
  {
    int split = b >> 6, iblk = b & 63;
    int i = iblk * 64 + wv * 16 + row16;
    float f1  = e11o[i];
    float f02 = e102o[i];
    int jbeg = split * 256;
    short8 bden;
    #pragma unroll
    for (int t = 0; t < 8; ++t) bden[t] = (row16 == 0) ? (short)0x3F80 : (short)0;

    f32x4 acc = {};
    f32x4 accden = {};
    #pragma unroll
    for (int c = 0; c < 4; ++c){
      int j0 = jbeg + c * 64;
      u64 mrow = adjbits[(size_t)i * 64 + (j0 >> 6)];
      #pragma unroll
      for (int ks = 0; ks < 2; ++ks){
        int sb = (j0 >> 3) + ks * 4 + grp;
        short8 bf = *(const short8*)(whoB + ((size_t)sb * 16 + row16) * 8);
        const float* t1 = e21o  + j0 + ks * 32 + grp * 8;
        const float* t2 = e202o + j0 + ks * 32 + grp * 8;
        float4 eA = *(const float4*)t1;
        float4 eB = *(const float4*)(t1 + 4);
        float4 gA = *(const float4*)t2;
        float4 gB = *(const float4*)(t2 + 4);
        float e1v[8] = {eA.x, eA.y, eA.z, eA.w, eB.x, eB.y, eB.z, eB.w};
        float e2v[8] = {gA.x, gA.y, gA.z, gA.w, gB.x, gB.y, gB.z, gB.w};
        u32 mb = ((u32)(mrow >> (ks * 32)) >> (grp * 8)) & 0xffu;
        u32 pk[4];
        #pragma unroll
        for (int t2i = 0; t2i < 4; ++t2i){
          float w0 = fmaxf(f1 * e1v[2 * t2i],     f02 * e2v[2 * t2i]);
          float w1 = fmaxf(f1 * e1v[2 * t2i + 1], f02 * e2v[2 * t2i + 1]);
          u32 p = __builtin_amdgcn_perm(__float_as_uint(w1), __float_as_uint(w0), 0x07060302u);
          pk[t2i] = p & s_lut[(mb >> (2 * t2i)) & 3u];
        }
        short8 af = *(short8*)pk;
        acc    = __builtin_amdgcn_mfma_f32_16x16x32_bf16(af, bf, acc, 0, 0, 0);
        accden = __builtin_amdgcn_mfma_f32_16x16x32_bf16(af, bden, accden, 0, 0, 0);
      }
    }
    #pragma unroll
    for (int r = 0; r < 4; ++r){
      int n = iblk * 64 + wv * 16 + grp * 4 + r;
      if (row16 == 0)
        pden2[(size_t)n * 16 + split] = accden[r];
      pnum2[((size_t)n * 16 + split) * 16 + row16] = acc[r];
    }
  }
  grid_barrier(bar);

  // ======================= P5: combine + elu + log_softmax =================
  if (b < 256){
    int t = b * 256 + tid;                    // 65536
    int c = t & 15;
    int n = t >> 4;
    float num = 0.f, den = 0.f;
    #pragma unroll
    for (int s = 0; s < 16; ++s){
      num += pnum2[((size_t)n * 16 + s) * 16 + c];
      den += pden2[(size_t)n * 16 + s];
    }
    float v = num / den;
    v = v > 0.f ? v : (__expf(v) - 1.f);
    float m = v;
    #pragma unroll
    for (int d = 1; d < 16; d <<= 1) m = fmaxf(m, __shfl_xor(m, d, 64));
    float es = __expf(v - m), ss = es;
    #pragma unroll
    for (int d = 1; d < 16; d <<= 1) ss += __shfl_xor(ss, d, 64);
    out[(size_t)n * 16 + c] = v - m - __logf(ss);
  }
}

// ---------------------------------------------------------------------------
extern "C" void kernel_launch(void* const* d_in, const int* in_sizes, int n_in,
                              void* d_out, int out_size, void* d_ws, size_t ws_size,
                              hipStream_t stream){
  (void)in_sizes; (void)n_in; (void)out_size; (void)ws_size;
  const float* x    = (const float*)d_in[0];
  const int*   adj  = (const int*)d_in[1];
  const float* W    = (const float*)d_in[2];
  const float* av   = (const float*)d_in[3];
  const float* Wout = (const float*)d_in[4];
  const float* aout = (const float*)d_in[5];
  float* out = (float*)d_out;
  char* ws = (char*)d_ws;

  u32*  bar     = (u32*)(ws + 0x0000000);        // 4 KB page
  u64*  adjbits = (u64*)(ws + 0x0010000);        // 2 MB
  u16*  whB     = (u16*)(ws + 0x0210000);        // 4 MB
  float* e11    = (float*)(ws + 0x0610000);      // 4 x 128 KB
  float* e102   = (float*)(ws + 0x0630000);
  float* e21    = (float*)(ws + 0x0650000);
  float* e202   = (float*)(ws + 0x0670000);
  // overlap region: xA/wB (P0-P1 only) alias pnum1 (written P2+)
  u16*  xA      = (u16*)(ws + 0x0690000);        // 4 MB
  u16*  wB      = (u16*)(ws + 0x0A90000);        // 512 KB
  u16*  pnum1   = (u16*)(ws + 0x0690000);        // 16 MB [4][4096][512] bf16
  float* pden1  = (float*)(ws + 0x1690000);      // 512 KB [4][8][4096]
  u16*  whoB    = (u16*)(ws + 0x1710000);        // 128 KB
  float* e11o   = (float*)(ws + 0x1730000);      // 4 x 16 KB
  float* e102o  = (float*)(ws + 0x1734000);
  float* e21o   = (float*)(ws + 0x1738000);
  float* e202o  = (float*)(ws + 0x173C000);
  float* pnum2  = (float*)(ws + 0x1740000);      // 4 MB [4096][16][16]
  float* pden2  = (float*)(ws + 0x1B40000);      // 256 KB

  hipMemsetAsync(ws, 0, 64, stream);             // reset grid-barrier state

  k_gat<<<dim3(NBLK), dim3(256), 0, stream>>>(
      x, adj, W, av, Wout, aout, out,
      bar, adjbits, xA, wB, whB, e11, e102, e21, e202,
      pnum1, pden1, whoB, e11o, e102o, e21o, e202o, pnum2, pden2);
}

// Round 7
// 191.725 us; speedup vs baseline: 6.7761x; 6.7761x over previous
//
#include <hip/hip_runtime.h>

// ---------------------------------------------------------------------------
// GAT (2-layer, dense mask) on gfx950 — R7.
// vs R3 (best, 194 us): (1) adjacency bitmask TRANSPOSED to bits_t[jg][i] so
// per-chunk mask loads are coalesced 128 B instead of 64-line gathers (the
// pathology shared by every ~60 us att1 variant); (2) att1 back to R2's
// winning tiling (2048 blocks, 1 A-tile/wave, LDS dbuf) with R3's cheaper
// inner loop; (3) adj-pack + input packs fused into one k_prep (6 launches).
// R6's persistent-kernel grid barrier livelocked (same-line arrive/poll,
// non-coherent XCD L2s) — abandoned.
// ---------------------------------------------------------------------------

typedef __attribute__((ext_vector_type(8))) short short8;   // 8 x bf16
typedef __attribute__((ext_vector_type(4))) float f32x4;
typedef unsigned long long u64;
typedef unsigned short u16;
typedef unsigned int u32;

__device__ __forceinline__ u16 f2bf_rne(float f){
  u32 u = __float_as_uint(f);
  return (u16)((u + 0x7fffu + ((u >> 16) & 1u)) >> 16);
}
__device__ __forceinline__ void async16(void* lds, const void* g){
  __builtin_amdgcn_global_load_lds((const __attribute__((address_space(1))) u32*)g,
                                   (__attribute__((address_space(3))) u32*)lds, 16, 0, 0);
}
__device__ __forceinline__ void async4(void* lds, const void* g){
  __builtin_amdgcn_global_load_lds((const __attribute__((address_space(1))) u32*)g,
                                   (__attribute__((address_space(3))) u32*)lds, 4, 0, 0);
}

// ------------------- K1: fused input packs + adj transpose-pack ------------
// b <  1024 : x -> bf16 A-layout
// b <  1152 : W -> bf16 B-layout
// b <  1664 : adj -> bits_t[jg][i]  (transposed bitmask, coalesced for att)
__global__ __launch_bounds__(256) void k_prep(const float* __restrict__ x,
                                              const float* __restrict__ W,
                                              const int* __restrict__ adj,
                                              u16* __restrict__ xA,
                                              u16* __restrict__ wB,
                                              u64* __restrict__ bits_t){
  int lane = threadIdx.x & 63;
  if (blockIdx.x < 1024){
    int t = blockIdx.x * 256 + threadIdx.x;           // 262144
    int n = t & 4095, fg = t >> 12;
    const float* src = x + (size_t)n * 512 + fg * 8;
    float4 v0 = ((const float4*)src)[0];
    float4 v1 = ((const float4*)src)[1];
    u32 pk[4];
    pk[0] = f2bf_rne(v0.x) | ((u32)f2bf_rne(v0.y) << 16);
    pk[1] = f2bf_rne(v0.z) | ((u32)f2bf_rne(v0.w) << 16);
    pk[2] = f2bf_rne(v1.x) | ((u32)f2bf_rne(v1.y) << 16);
    pk[3] = f2bf_rne(v1.z) | ((u32)f2bf_rne(v1.w) << 16);
    *(uint4*)(xA + ((size_t)fg * 4096 + n) * 8) = *(uint4*)pk;
  } else if (blockIdx.x < 1152){
    int t = (blockIdx.x - 1024) * 256 + threadIdx.x;  // 32768
    int o = t & 63, fg = (t >> 6) & 63, h = t >> 12;
    const float* src = W + ((size_t)h * 512 + fg * 8) * 64 + o;
    u32 pk[4];
    #pragma unroll
    for (int p = 0; p < 4; ++p){
      u16 lo = f2bf_rne(src[(2 * p) * 64]);
      u16 hi = f2bf_rne(src[(2 * p + 1) * 64]);
      pk[p] = lo | ((u32)hi << 16);
    }
    *(uint4*)(wB + (size_t)h * 32768 + ((size_t)fg * 64 + o) * 8) = *(uint4*)pk;
  } else {
    // adj transpose-pack: wave Wd handles jg = Wd>>5, i in [(Wd&31)*128, +128)
    int Wd = (blockIdx.x - 1152) * 4 + (threadIdx.x >> 6);   // 0..2047
    int jg = Wd >> 5;
    int i0 = (Wd & 31) * 128;
    const int* base = adj + (size_t)jg * 64 + lane;
    #pragma unroll 1
    for (int u = 0; u < 32; ++u){
      int ib = i0 + u * 4;
      int v0 = base[(size_t)(ib + 0) * 4096];
      int v1 = base[(size_t)(ib + 1) * 4096];
      int v2 = base[(size_t)(ib + 2) * 4096];
      int v3 = base[(size_t)(ib + 3) * 4096];
      u64 m0 = __ballot(v0 != 0);
      u64 m1 = __ballot(v1 != 0);
      u64 m2 = __ballot(v2 != 0);
      u64 m3 = __ballot(v3 != 0);
      if (lane == 0){
        u64* d = bits_t + (size_t)jg * 4096 + ib;
        d[0] = m0; d[1] = m1; d[2] = m2; d[3] = m3;
      }
    }
  }
}

// ------------------------- K2: Wh = x @ W[h]; fused tables + whB pack ------
__global__ __launch_bounds__(256) void k_gemm1(const u16* __restrict__ xA,
                                               const u16* __restrict__ wB,
                                               const float* __restrict__ av,
                                               u16* __restrict__ whB,
                                               float* __restrict__ e11, float* __restrict__ e102,
                                               float* __restrict__ e21, float* __restrict__ e202){
  __shared__ u16 tr[4096];                 // 64 x 64 bf16, whB sub-layout
  int h    = blockIdx.y;
  int nblk = blockIdx.x;
  int lane = threadIdx.x & 63;
  int wv   = threadIdx.x >> 6;
  int row16 = lane & 15, grp = lane >> 4;
  int n0 = nblk * 64;
  int n0w = n0 + wv * 16;
  const u16* wBh = wB + (size_t)h * 32768;
  f32x4 acc[4] = {};
  #pragma unroll 4
  for (int ks = 0; ks < 16; ++ks){
    int fgb = ks * 4 + grp;
    short8 af = *(const short8*)(xA + ((size_t)fgb * 4096 + n0w + row16) * 8);
    #pragma unroll
    for (int nt = 0; nt < 4; ++nt){
      short8 bf = *(const short8*)(wBh + ((size_t)fgb * 64 + nt * 16 + row16) * 8);
      acc[nt] = __builtin_amdgcn_mfma_f32_16x16x32_bf16(af, bf, acc[nt], 0, 0, 0);
    }
  }
  float a1v[4], a2v[4];
  #pragma unroll
  for (int nt = 0; nt < 4; ++nt){
    a1v[nt] = av[h * 128 + nt * 16 + row16];
    a2v[nt] = av[h * 128 + 64 + nt * 16 + row16];
  }
  #pragma unroll
  for (int r = 0; r < 4; ++r){
    float p1 = acc[0][r]*a1v[0] + acc[1][r]*a1v[1] + acc[2][r]*a1v[2] + acc[3][r]*a1v[3];
    float p2 = acc[0][r]*a2v[0] + acc[1][r]*a2v[1] + acc[2][r]*a2v[2] + acc[3][r]*a2v[3];
    #pragma unroll
    for (int d = 1; d < 16; d <<= 1){ p1 += __shfl_xor(p1, d, 64); p2 += __shfl_xor(p2, d, 64); }
    if (row16 == 0){
      int idx = h * 4096 + n0w + grp * 4 + r;
      e11[idx] = __expf(p1); e102[idx] = __expf(0.2f * p1);
      e21[idx] = __expf(p2); e202[idx] = __expf(0.2f * p2);
    }
  }
  #pragma unroll
  for (int nt = 0; nt < 4; ++nt)
    #pragma unroll
    for (int r = 0; r < 4; ++r){
      int jl = wv * 16 + grp * 4 + r;
      int o  = nt * 16 + row16;
      tr[((jl >> 3) * 64 + o) * 8 + (jl & 7)] = f2bf_rne(acc[nt][r]);
    }
  __syncthreads();
  u16* dst = whB + (size_t)h * 262144 + (size_t)n0 * 64;
  #pragma unroll
  for (int q = 0; q < 2; ++q)
    *(uint4*)(dst + (threadIdx.x * 2 + q) * 8) = *(const uint4*)(tr + (threadIdx.x * 2 + q) * 8);
}

// ------------------------- K3: layer-1 attention ---------------------------
// grid (64 iblk, 8 h, 4 split) = 2048 blocks; wave = 1 A-tile (16 i);
// LDS dbuf staging (stride 512, conflict-free); transposed coalesced masks.
__global__ __launch_bounds__(256) void k_att1(const u16* __restrict__ whB,
                                              const u64* __restrict__ bits_t,
                                              const float* __restrict__ e11, const float* __restrict__ e102,
                                              const float* __restrict__ e21, const float* __restrict__ e202,
                                              u16* __restrict__ pnum, float* __restrict__ pden){
  __shared__ u16  smB[2][4096];            // 64 j x 64 o, [j/8][o][j&7]
  __shared__ float smT[2][2][64];          // e21, e202
  __shared__ u32  smLut[4];
  int h     = blockIdx.y;
  int iblk  = blockIdx.x;
  int split = blockIdx.z;
  int lane = threadIdx.x & 63;
  int wv   = threadIdx.x >> 6;
  int row16 = lane & 15, grp = lane >> 4;
  if (threadIdx.x < 4)
    smLut[threadIdx.x] = ((threadIdx.x & 1) ? 0xFFFFu : 0u) | ((threadIdx.x & 2) ? 0xFFFF0000u : 0u);
  int i = iblk * 64 + wv * 16 + row16;
  int hoff = h * 4096;
  float f1  = e11[hoff + i];
  float f02 = e102[hoff + i];
  const u16* whBh = whB + (size_t)h * 262144;
  int jbeg = split * 1024;

  short8 bden;                             // ones-column B frag for den
  #pragma unroll
  for (int t = 0; t < 8; ++t) bden[t] = (row16 == 0) ? (short)0x3F80 : (short)0;

  auto stage = [&](int bb, int j0){
    const char* g = (const char*)whBh + (size_t)j0 * 128 + wv * 2048 + lane * 16;
    char* l = (char*)(&smB[bb][0]) + wv * 2048;
    async16(l, g);
    async16(l + 1024, g + 1024);
    if (wv == 0)      async4(&smT[bb][0][0], (const char*)(e21  + hoff + j0) + lane * 4);
    else if (wv == 1) async4(&smT[bb][1][0], (const char*)(e202 + hoff + j0) + lane * 4);
  };

  f32x4 acc[4] = {};
  f32x4 accden = {};
  stage(0, jbeg);
  for (int c = 0; c < 16; ++c){
    int bb = c & 1;
    u64 mrow = bits_t[(size_t)(split * 16 + c) * 4096 + i];   // coalesced
    __syncthreads();                       // buf bb staged; buf bb^1 free
    if (c < 15) stage(bb ^ 1, jbeg + (c + 1) * 64);
    #pragma unroll
    for (int ks = 0; ks < 2; ++ks){
      int kb = ks * 32 + grp * 8;
      float4 eA = *(const float4*)(&smT[bb][0][kb]);
      float4 eB = *(const float4*)(&smT[bb][0][kb + 4]);
      float4 gA = *(const float4*)(&smT[bb][1][kb]);
      float4 gB = *(const float4*)(&smT[bb][1][kb + 4]);
      float e1v[8] = {eA.x, eA.y, eA.z, eA.w, eB.x, eB.y, eB.z, eB.w};
      float e2v[8] = {gA.x, gA.y, gA.z, gA.w, gB.x, gB.y, gB.z, gB.w};
      const u16* bbase = &smB[bb][(ks * 4 + grp) * 512];
      short8 bf0 = *(const short8*)(bbase + (0 * 16 + row16) * 8);
      short8 bf1 = *(const short8*)(bbase + (1 * 16 + row16) * 8);
      short8 bf2 = *(const short8*)(bbase + (2 * 16 + row16) * 8);
      short8 bf3 = *(const short8*)(bbase + (3 * 16 + row16) * 8);
      u32 mb = ((u32)(mrow >> (ks * 32)) >> (grp * 8)) & 0xffu;
      u32 pk[4];
      #pragma unroll
      for (int t2i = 0; t2i < 4; ++t2i){
        float w0 = fmaxf(f1 * e1v[2 * t2i],     f02 * e2v[2 * t2i]);
        float w1 = fmaxf(f1 * e1v[2 * t2i + 1], f02 * e2v[2 * t2i + 1]);
        u32 p = __builtin_amdgcn_perm(__float_as_uint(w1), __float_as_uint(w0), 0x07060302u);
        pk[t2i] = p & smLut[(mb >> (2 * t2i)) & 3u];
      }
      short8 af = *(short8*)pk;
      acc[0] = __builtin_amdgcn_mfma_f32_16x16x32_bf16(af, bf0, acc[0], 0, 0, 0);
      acc[1] = __builtin_amdgcn_mfma_f32_16x16x32_bf16(af, bf1, acc[1], 0, 0, 0);
      acc[2] = __builtin_amdgcn_mfma_f32_16x16x32_bf16(af, bf2, acc[2], 0, 0, 0);
      acc[3] = __builtin_amdgcn_mfma_f32_16x16x32_bf16(af, bf3, acc[3], 0, 0, 0);
      accden = __builtin_amdgcn_mfma_f32_16x16x32_bf16(af, bden, accden, 0, 0, 0);
    }
  }

  #pragma unroll
  for (int r = 0; r < 4; ++r){
    int n = iblk * 64 + wv * 16 + grp * 4 + r;
    if (row16 == 0)
      pden[((size_t)split * 8 + h) * 4096 + n] = accden[r];
    u16* dst = pnum + ((size_t)split * 4096 + n) * 512 + h * 64 + row16;
    #pragma unroll
    for (int nt = 0; nt < 4; ++nt)
      dst[nt * 16] = f2bf_rne(acc[nt][r]);
  }
}

// ------------------------- K4: combine + Who=h@Wout + layer-2 tables -------
__global__ __launch_bounds__(256) void k_gemm2(const u16* __restrict__ pnum,
                                               const float* __restrict__ pden,
                                               const float* __restrict__ Wout,
                                               const float* __restrict__ aout,
                                               u16* __restrict__ whoB,
                                               float* __restrict__ e11o, float* __restrict__ e102o,
                                               float* __restrict__ e21o, float* __restrict__ e202o){
  __shared__ float Wl[8192];                  // 512 x 16
  __shared__ float hrow[16 * 516];            // combined+elu rows, padded stride
  __shared__ float sden[128];                 // den[h][n]
  int n0 = blockIdx.x * 16;
  for (int t = threadIdx.x; t < 8192; t += 256) Wl[t] = Wout[t];
  if (threadIdx.x < 128){
    int hh = threadIdx.x >> 4, nn = threadIdx.x & 15;
    float d = 0.f;
    #pragma unroll
    for (int s = 0; s < 4; ++s) d += pden[((size_t)s * 8 + hh) * 4096 + n0 + nn];
    sden[threadIdx.x] = d;
  }
  __syncthreads();
  {
    int nn = threadIdx.x >> 4;
    int fc = threadIdx.x & 15;
    int f0 = fc * 32;
    int hh = fc >> 1;
    float dinv = 1.f / sden[hh * 16 + nn];
    float v[32];
    #pragma unroll
    for (int k = 0; k < 32; ++k) v[k] = 0.f;
    #pragma unroll
    for (int s = 0; s < 4; ++s){
      const u16* p = pnum + ((size_t)s * 4096 + n0 + nn) * 512 + f0;
      #pragma unroll
      for (int q = 0; q < 4; ++q){
        uint4 raw = *(const uint4*)(p + q * 8);
        u32 rw[4] = {raw.x, raw.y, raw.z, raw.w};
        #pragma unroll
        for (int d2 = 0; d2 < 4; ++d2){
          v[q * 8 + d2 * 2]     += __uint_as_float(rw[d2] << 16);
          v[q * 8 + d2 * 2 + 1] += __uint_as_float(rw[d2] & 0xffff0000u);
        }
      }
    }
    #pragma unroll
    for (int k = 0; k < 32; ++k){
      float val = v[k] * dinv;
      val = val > 0.f ? val : (__expf(val) - 1.f);
      hrow[nn * 516 + f0 + k] = val;
    }
  }
  __syncthreads();
  int c  = threadIdx.x & 15;
  int rl = threadIdx.x >> 4;
  int n = n0 + rl;
  const float4* hr = (const float4*)(hrow + rl * 516);
  float acc = 0.f;
  #pragma unroll 8
  for (int f4 = 0; f4 < 128; ++f4){
    float4 hv = hr[f4];
    int f = f4 * 4;
    acc += hv.x * Wl[f * 16 + c] + hv.y * Wl[(f + 1) * 16 + c]
         + hv.z * Wl[(f + 2) * 16 + c] + hv.w * Wl[(f + 3) * 16 + c];
  }
  whoB[((size_t)(n >> 3) * 16 + c) * 8 + (n & 7)] = f2bf_rne(acc);
  float p1 = acc * aout[c], p2 = acc * aout[16 + c];
  #pragma unroll
  for (int d = 1; d < 16; d <<= 1){ p1 += __shfl_xor(p1, d, 64); p2 += __shfl_xor(p2, d, 64); }
  if (c == 0){
    e11o[n] = __expf(p1); e102o[n] = __expf(0.2f * p1);
    e21o[n] = __expf(p2); e202o[n] = __expf(0.2f * p2);
  }
}

// ------------------------- K5: layer-2 attention (16-way split) ------------
__global__ __launch_bounds__(256) void k_att2(const u16* __restrict__ whoB,
                                              const u64* __restrict__ bits_t,
                                              const float* __restrict__ e11o, const float* __restrict__ e102o,
                                              const float* __restrict__ e21o, const float* __restrict__ e202o,
                                              float* __restrict__ pnum, float* __restrict__ pden){
  __shared__ u32 smLut[4];
  int iblk  = blockIdx.x;
  int split = blockIdx.y;                     // 0..15
  int lane = threadIdx.x & 63;
  int wv   = threadIdx.x >> 6;
  int row16 = lane & 15, grp = lane >> 4;
  if (threadIdx.x < 4)
    smLut[threadIdx.x] = ((threadIdx.x & 1) ? 0xFFFFu : 0u) | ((threadIdx.x & 2) ? 0xFFFF0000u : 0u);
  __syncthreads();
  int i = iblk * 64 + wv * 16 + row16;
  float f1  = e11o[i];
  float f02 = e102o[i];
  int jbeg = split * 256;
  short8 bden;
  #pragma unroll
  for (int t = 0; t < 8; ++t) bden[t] = (row16 == 0) ? (short)0x3F80 : (short)0;

  f32x4 acc = {};
  f32x4 accden = {};
  #pragma unroll
  for (int c = 0; c < 4; ++c){
    int j0 = jbeg + c * 64;
    u64 mrow = bits_t[(size_t)(split * 4 + c) * 4096 + i];   // coalesced
    #pragma unroll
    for (int ks = 0; ks < 2; ++ks){
      int sb = (j0 >> 3) + ks * 4 + grp;
      short8 bf = *(const short8*)(whoB + ((size_t)sb * 16 + row16) * 8);
      const float* t1 = e21o  + j0 + ks * 32 + grp * 8;
      const float* t2 = e202o + j0 + ks * 32 + grp * 8;
      float4 eA = *(const float4*)t1;
      float4 eB = *(const float4*)(t1 + 4);
      float4 gA = *(const float4*)t2;
      float4 gB = *(const float4*)(t2 + 4);
      float e1v[8] = {eA.x, eA.y, eA.z, eA.w, eB.x, eB.y, eB.z, eB.w};
      float e2v[8] = {gA.x, gA.y, gA.z, gA.w, gB.x, gB.y, gB.z, gB.w};
      u32 mb = ((u32)(mrow >> (ks * 32)) >> (grp * 8)) & 0xffu;
      u32 pk[4];
      #pragma unroll
      for (int t2i = 0; t2i < 4; ++t2i){
        float w0 = fmaxf(f1 * e1v[2 * t2i],     f02 * e2v[2 * t2i]);
        float w1 = fmaxf(f1 * e1v[2 * t2i + 1], f02 * e2v[2 * t2i + 1]);
        u32 p = __builtin_amdgcn_perm(__float_as_uint(w1), __float_as_uint(w0), 0x07060302u);
        pk[t2i] = p & smLut[(mb >> (2 * t2i)) & 3u];
      }
      short8 af = *(short8*)pk;
      acc    = __builtin_amdgcn_mfma_f32_16x16x32_bf16(af, bf, acc, 0, 0, 0);
      accden = __builtin_amdgcn_mfma_f32_16x16x32_bf16(af, bden, accden, 0, 0, 0);
    }
  }
  #pragma unroll
  for (int r = 0; r < 4; ++r){
    int n = iblk * 64 + wv * 16 + grp * 4 + r;
    if (row16 == 0)
      pden[(size_t)n * 16 + split] = accden[r];
    pnum[((size_t)n * 16 + split) * 16 + row16] = acc[r];
  }
}

// ------------------------- K6: combine + elu + log_softmax -----------------
__global__ __launch_bounds__(256) void k_final(const float* __restrict__ pnum,
                                               const float* __restrict__ pden,
                                               float* __restrict__ out){
  int tid = blockIdx.x * 256 + threadIdx.x;   // 65536
  int c = tid & 15;
  int n = tid >> 4;
  float num = 0.f, den = 0.f;
  #pragma unroll
  for (int s = 0; s < 16; ++s){
    num += pnum[((size_t)n * 16 + s) * 16 + c];
    den += pden[(size_t)n * 16 + s];
  }
  float v = num / den;
  v = v > 0.f ? v : (__expf(v) - 1.f);
  float m = v;
  #pragma unroll
  for (int d = 1; d < 16; d <<= 1) m = fmaxf(m, __shfl_xor(m, d, 64));
  float es = __expf(v - m), ss = es;
  #pragma unroll
  for (int d = 1; d < 16; d <<= 1) ss += __shfl_xor(ss, d, 64);
  out[(size_t)n * 16 + c] = v - m - __logf(ss);
}

// ---------------------------------------------------------------------------
extern "C" void kernel_launch(void* const* d_in, const int* in_sizes, int n_in,
                              void* d_out, int out_size, void* d_ws, size_t ws_size,
                              hipStream_t stream){
  (void)in_sizes; (void)n_in; (void)out_size; (void)ws_size;
  const float* x    = (const float*)d_in[0];
  const int*   adj  = (const int*)d_in[1];
  const float* W    = (const float*)d_in[2];
  const float* av   = (const float*)d_in[3];
  const float* Wout = (const float*)d_in[4];
  const float* aout = (const float*)d_in[5];
  float* out = (float*)d_out;
  char* ws = (char*)d_ws;

  u64*  bits_t  = (u64*)(ws + 0x0000000);        // 2 MB [64][4096]
  u16*  whB     = (u16*)(ws + 0x0200000);        // 4 MB
  float* e11    = (float*)(ws + 0x0600000);      // 4 x 128 KB exp tables
  float* e102   = (float*)(ws + 0x0620000);
  float* e21    = (float*)(ws + 0x0640000);
  float* e202   = (float*)(ws + 0x0660000);
  // overlap region: xA/wB (prep+gemm1 only) alias pnum1 (written att1+)
  u16*  xA      = (u16*)(ws + 0x0680000);        // 4 MB
  u16*  wB      = (u16*)(ws + 0x0A80000);        // 512 KB
  u16*  pnum1   = (u16*)(ws + 0x0680000);        // 16 MB [4][4096][512] bf16
  float* pden1  = (float*)(ws + 0x1680000);      // 512 KB [4][8][4096]
  u16*  whoB    = (u16*)(ws + 0x1700000);        // 128 KB
  float* e11o   = (float*)(ws + 0x1720000);      // 4 x 16 KB
  float* e102o  = (float*)(ws + 0x1724000);
  float* e21o   = (float*)(ws + 0x1728000);
  float* e202o  = (float*)(ws + 0x172C000);
  float* pnum2  = (float*)(ws + 0x1730000);      // 4 MB [4096][16][16]
  float* pden2  = (float*)(ws + 0x1B30000);      // 256 KB

  k_prep<<<dim3(1664), dim3(256), 0, stream>>>(x, W, adj, xA, wB, bits_t);
  k_gemm1<<<dim3(64, 8), dim3(256), 0, stream>>>(xA, wB, av, whB, e11, e102, e21, e202);
  k_att1<<<dim3(64, 8, 4), dim3(256), 0, stream>>>(whB, bits_t, e11, e102, e21, e202, pnum1, pden1);
  k_gemm2<<<dim3(256), dim3(256), 0, stream>>>(pnum1, pden1, Wout, aout, whoB, e11o, e102o, e21o, e202o);
  k_att2<<<dim3(64, 16), dim3(256), 0, stream>>>(whoB, bits_t, e11o, e102o, e21o, e202o, pnum2, pden2);
  k_final<<<dim3(256), dim3(256), 0, stream>>>(pnum2, pden2, out);
}